// Round 1
// baseline (291.029 us; speedup 1.0000x reference)
//
#include <hip/hip_runtime.h>
#include <hip/hip_bf16.h>

#define B_SZ 100000
#define NTOT 200000
#define NN   1000000
#define DIM  128

typedef short bf16x8 __attribute__((ext_vector_type(8)));
typedef float f32x4  __attribute__((ext_vector_type(4)));

__device__ __forceinline__ short f2bf(float f) {
    union { float f; unsigned u; } v; v.f = f;
    unsigned u = v.u;
    u += 0x7fffu + ((u >> 16) & 1u);
    return (short)(u >> 16);
}

// owner[node] = -1 for untouched
__global__ void k_init(int* __restrict__ owner) {
    int i = blockIdx.x * 256 + threadIdx.x;
    if (i < NN) owner[i] = -1;
}

// winner = max global code; src codes [0,B), dst codes [B,2B) -> dst beats src,
// later batch index beats earlier: matches numpy sequential scatter semantics.
__global__ void k_claim(const int* __restrict__ src, const int* __restrict__ dst,
                        int* __restrict__ owner) {
    int i = blockIdx.x * 256 + threadIdx.x;
    if (i >= NTOT) return;
    int node = (i < B_SZ) ? src[i] : dst[i - B_SZ];
    atomicMax(&owner[node], i);
}

// Pack B operands in MFMA fragment layout:
//  frag (kc,nc): lane l holds col n = nc*16 + (l&15), k = kc*32 + (l>>4)*8 + i (i=0..7)
//  PA[k][n] = W_node[n][k] + (k==n)      (applied to prev)
//  PQ[k][n] = sum_m W_node[n][m]*W_nig[m][k]   (applied to nbr)
//  cvec[n]  = b_node[n] + sum_k b_nig[k]*W_node[n][k]
__global__ void k_weights(const float* __restrict__ Wnig, const float* __restrict__ bnig,
                          const float* __restrict__ Wnode, const float* __restrict__ bnode,
                          short* __restrict__ PA, short* __restrict__ PQ,
                          float* __restrict__ cvec) {
    int b = blockIdx.x, t = threadIdx.x;
    if (b < 32) {
        int kc = b >> 3, nc = b & 7;
        int n = nc * 16 + (t & 15);
        int kbase = kc * 32 + (t >> 4) * 8;
        int fo = (b * 64 + t) * 8;
        for (int i = 0; i < 8; ++i) {
            int k = kbase + i;
            float a = Wnode[n * DIM + k] + (k == n ? 1.0f : 0.0f);
            PA[fo + i] = f2bf(a);
            float q = 0.f;
            for (int m = 0; m < DIM; ++m) q += Wnode[n * DIM + m] * Wnig[m * DIM + k];
            PQ[fo + i] = f2bf(q);
        }
    } else {
        for (int j = t; j < DIM; j += 64) {
            float c = bnode[j];
            for (int k = 0; k < DIM; ++k) c += bnig[k] * Wnode[j * DIM + k];
            cvec[j] = c;
        }
    }
}

// One wave per 16-row tile. A fragment: lane l -> row = l&15, k = kc*32+(l>>4)*8+i.
// D fragment: lane l -> col = l&15 (within nc block), row = (l>>4)*4 + r.
__global__ __launch_bounds__(256) void k_main(
        const int* __restrict__ src, const int* __restrict__ dst,
        const float* __restrict__ prev,
        const float* __restrict__ nsrc, const float* __restrict__ ndst,
        const int* __restrict__ owner,
        const short* __restrict__ PA, const short* __restrict__ PQ,
        const float* __restrict__ cvec,
        float* __restrict__ out) {
    int wave = threadIdx.x >> 6;
    int lane = threadIdx.x & 63;
    int rowbase = (blockIdx.x * 4 + wave) * 16;

    // A-operand row for this lane
    int arow = rowbase + (lane & 15);
    bool is_src = arow < B_SZ;
    int bi = is_src ? arow : arow - B_SZ;
    const int* ids = is_src ? src : dst;
    const float* nbr = is_src ? nsrc : ndst;
    int node_a = ids[bi];
    const float* prow = prev + (long)node_a * DIM;
    const float* nrow = nbr + (long)bi * DIM;
    int koff = (lane >> 4) * 8;

    f32x4 acc[8];
#pragma unroll
    for (int nc = 0; nc < 8; ++nc) acc[nc] = (f32x4){0.f, 0.f, 0.f, 0.f};

#pragma unroll
    for (int kc = 0; kc < 4; ++kc) {
        int k0 = kc * 32 + koff;
        float4 p0 = *(const float4*)(prow + k0);
        float4 p1 = *(const float4*)(prow + k0 + 4);
        float4 n0 = *(const float4*)(nrow + k0);
        float4 n1 = *(const float4*)(nrow + k0 + 4);
        bf16x8 aP, aN;
        aP[0] = f2bf(p0.x); aP[1] = f2bf(p0.y); aP[2] = f2bf(p0.z); aP[3] = f2bf(p0.w);
        aP[4] = f2bf(p1.x); aP[5] = f2bf(p1.y); aP[6] = f2bf(p1.z); aP[7] = f2bf(p1.w);
        aN[0] = f2bf(n0.x); aN[1] = f2bf(n0.y); aN[2] = f2bf(n0.z); aN[3] = f2bf(n0.w);
        aN[4] = f2bf(n1.x); aN[5] = f2bf(n1.y); aN[6] = f2bf(n1.z); aN[7] = f2bf(n1.w);
#pragma unroll
        for (int nc = 0; nc < 8; ++nc) {
            int fo = ((kc * 8 + nc) * 64 + lane) * 8;
            bf16x8 bA = *(const bf16x8*)(PA + fo);
            bf16x8 bQ = *(const bf16x8*)(PQ + fo);
            acc[nc] = __builtin_amdgcn_mfma_f32_16x16x32_bf16(aP, bA, acc[nc], 0, 0, 0);
            acc[nc] = __builtin_amdgcn_mfma_f32_16x16x32_bf16(aN, bQ, acc[nc], 0, 0, 0);
        }
    }

    // epilogue: write only winner rows
    int col0 = lane & 15;
    float cv[8];
#pragma unroll
    for (int nc = 0; nc < 8; ++nc) cv[nc] = cvec[nc * 16 + col0];

#pragma unroll
    for (int r = 0; r < 4; ++r) {
        int row = rowbase + (lane >> 4) * 4 + r;
        bool s = row < B_SZ;
        int b2 = s ? row : row - B_SZ;
        int node = (s ? src : dst)[b2];
        if (owner[node] == row) {
            float* orow = out + (long)node * DIM;
#pragma unroll
            for (int nc = 0; nc < 8; ++nc) {
                orow[nc * 16 + col0] = acc[nc][r] + cv[nc];
            }
        }
    }
}

// copy untouched rows; 32 lanes (float4 each) per row
__global__ void k_copy(const float* __restrict__ prev, const int* __restrict__ owner,
                       float* __restrict__ out) {
    long t = (long)blockIdx.x * blockDim.x + threadIdx.x;
    long stride = (long)gridDim.x * blockDim.x;
    const long total = (long)NN * 32;
    for (; t < total; t += stride) {
        int row = (int)(t >> 5);
        if (owner[row] < 0) {
            int c = (int)(t & 31);
            float4 v = ((const float4*)prev)[(long)row * 32 + c];
            ((float4*)out)[(long)row * 32 + c] = v;
        }
    }
}

extern "C" void kernel_launch(void* const* d_in, const int* in_sizes, int n_in,
                              void* d_out, int out_size, void* d_ws, size_t ws_size,
                              hipStream_t stream) {
    const int*   src  = (const int*)d_in[0];
    const int*   dst  = (const int*)d_in[1];
    const float* prev = (const float*)d_in[2];
    const float* nsrc = (const float*)d_in[3];
    const float* ndst = (const float*)d_in[4];
    const float* Wnig = (const float*)d_in[5];
    const float* bnig = (const float*)d_in[6];
    const float* Wnode = (const float*)d_in[7];
    const float* bnode = (const float*)d_in[8];
    float* out = (float*)d_out;

    // workspace layout
    const size_t OWNER_B = (size_t)NN * 4;         // 4,000,000
    const size_t PA_B = 32 * 64 * 8 * 2;           // 32768
    if (ws_size < OWNER_B + 2 * PA_B + 512) return; // insufficient scratch
    char* ws = (char*)d_ws;
    int*   owner = (int*)ws;
    short* PA = (short*)(ws + OWNER_B);
    short* PQ = (short*)(ws + OWNER_B + PA_B);
    float* cvec = (float*)(ws + OWNER_B + 2 * PA_B);

    k_init<<<(NN + 255) / 256, 256, 0, stream>>>(owner);
    k_claim<<<(NTOT + 255) / 256, 256, 0, stream>>>(src, dst, owner);
    k_weights<<<33, 64, 0, stream>>>(Wnig, bnig, Wnode, bnode, PA, PQ, cvec);
    k_main<<<3125, 256, 0, stream>>>(src, dst, prev, nsrc, ndst, owner, PA, PQ, cvec, out);
    k_copy<<<2048, 256, 0, stream>>>(prev, owner, out);
}